// Round 8
// baseline (196.960 us; speedup 1.0000x reference)
//
#include <hip/hip_runtime.h>

// SINDy: out[65536,32] = Theta(z)[65536,6545] @ (Xi*Xi_mask)[6545,32]
// Round-8: all-LDS 3-stage pipelined K-loop (no SMEM in the hot path -> no
// lgkmcnt(0) serialization), guard-free inner loop (padded tables absorb
// tail overreads), split-K x4 with quarter-aligned ranges, bounds(256,5).
// MFMA 32x32x16_bf16 layouts (verified rounds 1-7):
//   A[m][k]: m=lane&31, k=(lane>>5)*8+jj
//   B[k][n]: n=lane&31, k=(lane>>5)*8+jj
//   C/D:     col=lane&31, row=(reg&3)+8*(reg>>2)+4*(lane>>5)

#define Z 32
#define ROWS 65536
#define NBLK (ROWS / 32)         // 2048 blocks, one 32x32 tile, 4 k-splits

#define NCHUNK 552               // quarters: 36 + 84 + 160 + 272
#define NGRAN (NCHUNK * 2)
#define NGP 1168                 // padded granule count (tail overreads -> 0)

typedef short short8 __attribute__((ext_vector_type(8)));
typedef float f32x16 __attribute__((ext_vector_type(16)));
typedef float float2v __attribute__((ext_vector_type(2)));

struct alignas(4) Sched {
    unsigned short mgi[NGP];   // (i*128) byte offset into col-major zs; pad=0
    unsigned short mgj[NGP];   // (j*128)
    short rt[NGRAN * 8];       // library row per (granule, jj), -1 = pad
    int nq[4];
};

constexpr Sched make_sched() {
    Sched s{};
    short gi[NGP] = {}, gj[NGP] = {};
    char gt[NGP] = {}, gq[NGP] = {};
    int tidx[32][32] = {}, pidx[32] = {};
    {
        int n = 0;
        for (int a = 0; a < 32; ++a)
            for (int b = a; b < 32; ++b) { tidx[a][b] = n; n += 32 - b; }
        for (int i = 0; i < 32; ++i) pidx[i] = i * 32 - i * (i - 1) / 2;
    }
    int g = 0;
    for (int q = 0; q < 4; ++q) {
        int g0 = g;
        // triples (a<=b): granule covers k in [8q,8q+8) for k>=b -> b>>3 <= q
        for (int b = 0; b < 32; ++b)
            if ((b >> 3) <= q)
                for (int a = 0; a <= b; ++a) { gi[g]=(short)a; gj[g]=(short)b; gt[g]=0; gq[g]=(char)q; ++g; }
        // pairs (b,32): theta = z_b*z_k, valid k<=b -> b>>3 >= q
        for (int b = 0; b < 32; ++b)
            if ((b >> 3) >= q) { gi[g]=(short)b; gj[g]=32; gt[g]=1; gq[g]=(char)q; ++g; }
        // linear: theta = z_k
        gi[g]=32; gj[g]=32; gt[g]=2; gq[g]=(char)q; ++g;
        // pad quarter to a multiple of 8 granules (4 chunks)
        while ((g - g0) & 7) { gi[g]=32; gj[g]=32; gt[g]=3; gq[g]=(char)q; ++g; }
        s.nq[q] = (g - g0) / 2;
    }
    for (int gg = 0; gg < NGRAN; ++gg) {
        s.mgi[gg] = (unsigned short)(gi[gg] * 128);
        s.mgj[gg] = (unsigned short)(gj[gg] * 128);
        int i = gi[gg], j = gj[gg], ty = gt[gg], q = gq[gg];
        for (int jj = 0; jj < 8; ++jj) {
            int k = 8 * q + jj, row = -1;
            if (ty == 0)      { if (k >= j) row = 561 + tidx[i][j] + (k - j); }   // triple (i,j,k)
            else if (ty == 1) { if (k <= i) row = 33 + pidx[k] + (i - k); }       // pair (k,i)
            else if (ty == 2) { row = 1 + k; }                                    // linear z_k
            s.rt[gg * 8 + jj] = (short)row;
        }
    }
    // pad region [NGRAN,NGP): mgi/mgj stay 0 -> reads hit zs[0][m], unused
    return s;
}
constexpr Sched S = make_sched();
static_assert(S.nq[0] == 36 && S.nq[1] == 84 && S.nq[2] == 160 && S.nq[3] == 272, "chunk counts");

__device__ __forceinline__ unsigned pack_bf16(float s0, float s1) {
#if __has_builtin(__builtin_amdgcn_cvt_pk_bf16_f32)
    return __builtin_bit_cast(unsigned, __builtin_amdgcn_cvt_pk_bf16_f32(s0, s1));
#else
    unsigned b0 = __builtin_bit_cast(unsigned, s0) + 0x8000u;
    unsigned b1 = __builtin_bit_cast(unsigned, s1) + 0x8000u;
    return __builtin_amdgcn_perm(b1, b0, 0x07060302u);   // lo16=s0, hi16=s1
#endif
}

// ---- prep (unchanged from R7: coalesced, proven) ----
__global__ void sindy_prep(const float* __restrict__ Xi,
                           const float* __restrict__ Xi_mask,
                           uint2* __restrict__ Bp2, size_t ws_size) {
    __shared__ unsigned short sh[8][32];
    const int tid = threadIdx.x;
    const int jj = tid >> 5, n = tid & 31;
#pragma unroll
    for (int pass = 0; pass < 4; ++pass) {
        int g = blockIdx.x * 4 + pass;
        int row = S.rt[g * 8 + jj];
        float f = 0.0f;
        if (row >= 0) f = Xi[row * Z + n] * Xi_mask[row * Z + n];
        unsigned u = __builtin_bit_cast(unsigned, f);
        sh[jj][n] = (unsigned short)((u + 0x7FFFu + ((u >> 16) & 1u)) >> 16);  // RNE
        __syncthreads();
        if (tid < 64) {
            int n2 = tid & 31, rep = tid >> 5;
            unsigned v0 = sh[4*rep+0][n2], v1 = sh[4*rep+1][n2];
            unsigned v2 = sh[4*rep+2][n2], v3 = sh[4*rep+3][n2];
            int c = g >> 1, h = g & 1;
            size_t idx = ((size_t)c * 64 + h * 32 + n2) * 2 + rep;
            if ((idx + 1) * 8 <= ws_size)
                Bp2[idx] = uint2{v0 | (v1 << 16), v2 | (v3 << 16)};
        }
        __syncthreads();
    }
}

// 3-stage pipeline state (scalars only — R4 spill lesson)
struct Pipe {
    float p0, p1, p2, p3;              // products for current SG
    float zi0, zj0, zi1, zj1, zi2, zj2, zi3, zj3;   // z vals for SG+1
    int ui0, uj0, ui1, uj1, ui2, uj2, ui3, uj3;     // u16 offs for SG+2
};

// ---- segment runner: guard-free steady loop; pipeline stays warm across calls ----
template<int Q, bool LASTP>
__device__ __forceinline__ void seg_run(int c0, int nSG, Pipe& P,
                                        const unsigned short* __restrict__ mi,
                                        const unsigned short* __restrict__ mj,
                                        const char* __restrict__ zmb,
                                        const uint4*& p,
                                        uint4& cur0, uint4& cur1, uint4& cur2, uint4& cur3,
                                        f32x16& acc) {
    // this quarter's z octet (static offsets)
    float2v zqA, zqB, zqC, zqD;
    zqA.x = *(const float*)(zmb + (8*Q+0)*128); zqA.y = *(const float*)(zmb + (8*Q+1)*128);
    zqB.x = *(const float*)(zmb + (8*Q+2)*128); zqB.y = *(const float*)(zmb + (8*Q+3)*128);
    zqC.x = *(const float*)(zmb + (8*Q+4)*128); zqC.y = *(const float*)(zmb + (8*Q+5)*128);
    zqD.x = *(const float*)(zmb + (8*Q+6)*128); zqD.y = *(const float*)(zmb + (8*Q+7)*128);

    auto chunk = [&](float pp, const uint4& bv) {
        float2v p2; p2.x = pp; p2.y = pp;
        union { unsigned u[4]; short8 sv; } a;
        float2v t0 = p2 * zqA; a.u[0] = pack_bf16(t0.x, t0.y);
        float2v t1 = p2 * zqB; a.u[1] = pack_bf16(t1.x, t1.y);
        float2v t2 = p2 * zqC; a.u[2] = pack_bf16(t2.x, t2.y);
        float2v t3 = p2 * zqD; a.u[3] = pack_bf16(t3.x, t3.y);
        union { uint4 v; short8 sv; } b; b.v = bv;
        acc = __builtin_amdgcn_mfma_f32_32x32x16_bf16(a.sv, b.sv, acc, 0, 0, 0);
    };

    for (int s = 0; s < nSG; ++s) {
        const int cc = c0 + 4 * s;
        // stage 1: u16 offsets for SG+3 (padded tables absorb overreads)
        int ni0 = mi[2*(cc+12)+0], nj0 = mj[2*(cc+12)+0];
        int ni1 = mi[2*(cc+12)+2], nj1 = mj[2*(cc+12)+2];
        int ni2 = mi[2*(cc+12)+4], nj2 = mj[2*(cc+12)+4];
        int ni3 = mi[2*(cc+12)+6], nj3 = mj[2*(cc+12)+6];
        // stage 2: z reads for SG+2 from staged offsets
        float wzi0 = *(const float*)(zmb + P.ui0), wzj0 = *(const float*)(zmb + P.uj0);
        float wzi1 = *(const float*)(zmb + P.ui1), wzj1 = *(const float*)(zmb + P.uj1);
        float wzi2 = *(const float*)(zmb + P.ui2), wzj2 = *(const float*)(zmb + P.uj2);
        float wzi3 = *(const float*)(zmb + P.ui3), wzj3 = *(const float*)(zmb + P.uj3);
        // stage 3: B prefetch for SG+1 (clamped only in the final SG of the wave)
        int offn = (LASTP && s == nSG - 1) ? 0 : 256;
        uint4 n0 = p[offn], n1 = p[offn + 64], n2 = p[offn + 128], n3 = p[offn + 192];
        // MFMA block for current SG
        chunk(P.p0, cur0); chunk(P.p1, cur1); chunk(P.p2, cur2); chunk(P.p3, cur3);
        // retire stages
        P.p0 = P.zi0 * P.zj0; P.p1 = P.zi1 * P.zj1;
        P.p2 = P.zi2 * P.zj2; P.p3 = P.zi3 * P.zj3;
        P.zi0 = wzi0; P.zj0 = wzj0; P.zi1 = wzi1; P.zj1 = wzj1;
        P.zi2 = wzi2; P.zj2 = wzj2; P.zi3 = wzi3; P.zj3 = wzj3;
        P.ui0 = ni0; P.uj0 = nj0; P.ui1 = ni1; P.uj1 = nj1;
        P.ui2 = ni2; P.uj2 = nj2; P.ui3 = ni3; P.uj3 = nj3;
        cur0 = n0; cur1 = n1; cur2 = n2; cur3 = n3;
        p += offn;
    }
}

// ---- main: 256 thr = 4 waves = 1 tile x 4 k-splits [0,136,280,416,552) ----
__global__ __launch_bounds__(256, 5) void sindy_mfma(const float* __restrict__ z,
                                                     const float* __restrict__ Xi,
                                                     const float* __restrict__ Xi_mask,
                                                     const uint4* __restrict__ Bp,
                                                     float* __restrict__ out) {
    const int lane = threadIdx.x & 63;
    const int kh = threadIdx.x >> 6;     // k-split 0..3
    const int m = lane & 31;
    const int half = lane >> 5;
    const long R = (long)blockIdx.x * 32;

    __shared__ float zs[33][32];         // col-major zs[k][m]; bank=m
    __shared__ float cs[2][32][32];      // partials from kh1 / kh3
    __shared__ unsigned short mgi_sh[NGP], mgj_sh[NGP];

    // stage z col-major: wave kh writes k in [8kh, 8kh+8)
    {
        const float4* z4 = (const float4*)(z + (R + m) * Z + 8 * kh);
        float4 v0 = z4[0], v1 = z4[1];
        zs[8*kh+0][m] = v0.x; zs[8*kh+1][m] = v0.y; zs[8*kh+2][m] = v0.z; zs[8*kh+3][m] = v0.w;
        zs[8*kh+4][m] = v1.x; zs[8*kh+5][m] = v1.y; zs[8*kh+6][m] = v1.z; zs[8*kh+7][m] = v1.w;
        if (kh == 0 && half == 0) zs[32][m] = 1.0f;   // z~[32] = 1.0 sentinel
    }
    // stage meta tables (u32 copies of rodata)
    for (int t = threadIdx.x; t < NGP / 2; t += 256) {
        ((unsigned*)mgi_sh)[t] = ((const unsigned*)S.mgi)[t];
        ((unsigned*)mgj_sh)[t] = ((const unsigned*)S.mgj)[t];
    }
    __syncthreads();

    const int c0 = (kh == 0) ? 0 : (kh == 1) ? 136 : (kh == 2) ? 280 : 416;
    const unsigned short* mi = &mgi_sh[half];
    const unsigned short* mj = &mgj_sh[half];
    const char* zmb = (const char*)&zs[0][0] + 4 * m;

    // prime pipeline: products(SG0), z(SG1), u16(SG2); B(SG0)
    Pipe P;
    {
        int a0 = mi[2*c0+0], b0 = mj[2*c0+0], a1 = mi[2*c0+2], b1 = mj[2*c0+2];
        int a2 = mi[2*c0+4], b2 = mj[2*c0+4], a3 = mi[2*c0+6], b3 = mj[2*c0+6];
        P.p0 = (*(const float*)(zmb + a0)) * (*(const float*)(zmb + b0));
        P.p1 = (*(const float*)(zmb + a1)) * (*(const float*)(zmb + b1));
        P.p2 = (*(const float*)(zmb + a2)) * (*(const float*)(zmb + b2));
        P.p3 = (*(const float*)(zmb + a3)) * (*(const float*)(zmb + b3));
        int c1 = c0 + 4;
        int e0 = mi[2*c1+0], f0 = mj[2*c1+0], e1 = mi[2*c1+2], f1 = mj[2*c1+2];
        int e2 = mi[2*c1+4], f2 = mj[2*c1+4], e3 = mi[2*c1+6], f3 = mj[2*c1+6];
        P.zi0 = *(const float*)(zmb + e0); P.zj0 = *(const float*)(zmb + f0);
        P.zi1 = *(const float*)(zmb + e1); P.zj1 = *(const float*)(zmb + f1);
        P.zi2 = *(const float*)(zmb + e2); P.zj2 = *(const float*)(zmb + f2);
        P.zi3 = *(const float*)(zmb + e3); P.zj3 = *(const float*)(zmb + f3);
        int c2 = c0 + 8;
        P.ui0 = mi[2*c2+0]; P.uj0 = mj[2*c2+0]; P.ui1 = mi[2*c2+2]; P.uj1 = mj[2*c2+2];
        P.ui2 = mi[2*c2+4]; P.uj2 = mj[2*c2+4]; P.ui3 = mi[2*c2+6]; P.uj3 = mj[2*c2+6];
    }
    const uint4* p = Bp + lane + (size_t)c0 * 64;
    uint4 cur0 = p[0], cur1 = p[64], cur2 = p[128], cur3 = p[192];

    f32x16 acc = {};
    if (kh == 0) {
        seg_run<0, false>(  0,  9, P, mi, mj, zmb, p, cur0, cur1, cur2, cur3, acc);
        seg_run<1, false>( 36, 21, P, mi, mj, zmb, p, cur0, cur1, cur2, cur3, acc);
        seg_run<2, true >(120,  4, P, mi, mj, zmb, p, cur0, cur1, cur2, cur3, acc);
    } else if (kh == 1) {
        seg_run<2, true >(136, 36, P, mi, mj, zmb, p, cur0, cur1, cur2, cur3, acc);
    } else if (kh == 2) {
        seg_run<3, true >(280, 34, P, mi, mj, zmb, p, cur0, cur1, cur2, cur3, acc);
    } else {
        seg_run<3, true >(416, 34, P, mi, mj, zmb, p, cur0, cur1, cur2, cur3, acc);
    }

    // combine: kh1 -> cs[0], kh3 -> cs[1]
    if (kh == 1 || kh == 3) {
        float (*dst)[32] = cs[kh >> 1];
#pragma unroll
        for (int r = 0; r < 16; ++r) {
            int row = (r & 3) + 8 * (r >> 2) + 4 * half;
            dst[row][m] = acc[r];
        }
    }
    __syncthreads();
    if (kh == 0) {
#pragma unroll
        for (int r = 0; r < 16; ++r) {
            int row = (r & 3) + 8 * (r >> 2) + 4 * half;
            acc[r] += cs[0][row][m];
        }
    } else if (kh == 2) {
#pragma unroll
        for (int r = 0; r < 16; ++r) {
            int row = (r & 3) + 8 * (r >> 2) + 4 * half;
            cs[1][row][m] += acc[r];   // in-place: same lane, same addr
        }
    }
    __syncthreads();
    if (kh == 0) {
        const float bias = Xi[m] * Xi_mask[m];   // library row 0 (ones), col n = m
        float* orow = out + R * Z;
#pragma unroll
        for (int r = 0; r < 16; ++r) {
            int row = (r & 3) + 8 * (r >> 2) + 4 * half;
            orow[row * Z + m] = acc[r] + cs[1][row][m] + bias;
        }
    }
}

extern "C" void kernel_launch(void* const* d_in, const int* in_sizes, int n_in,
                              void* d_out, int out_size, void* d_ws, size_t ws_size,
                              hipStream_t stream) {
    const float* z       = (const float*)d_in[0];
    const float* Xi      = (const float*)d_in[1];
    const float* Xi_mask = (const float*)d_in[2];
    // d_in[3]=z_mean, d_in[4]=z_std: unused by the reference
    float* out = (float*)d_out;
    uint4* Bp  = (uint4*)d_ws;   // NCHUNK*64*16 = 565,248 bytes

    sindy_prep<<<NGRAN / 4, 256, 0, stream>>>(Xi, Xi_mask, (uint2*)d_ws, ws_size);
    sindy_mfma<<<NBLK, 256, 0, stream>>>(z, Xi, Xi_mask, Bp, out);
}

// Round 9
// 124.931 us; speedup vs baseline: 1.5765x; 1.5765x over previous
//
#include <hip/hip_runtime.h>

// SINDy: out[65536,32] = Theta(z)[65536,6545] @ (Xi*Xi_mask)[6545,32]
// Round-9: 2 output tiles per wave -> B fragment + meta word shared across
// tiles, 4 MFMAs (128 cyc issue) per iteration vs ~90 cyc overhead: MFMA
// issue becomes the limiter by construction. Split-K x4 (138 chunks each,
// exactly balanced), all-LDS meta (R6 lesson: no SMEM in hot loop), shallow
// R6-style pipeline with plain-scalar state in ONE function scope (R4/R8
// lesson: no struct/array pipeline state -> no scratch).
// MFMA 32x32x16_bf16 layouts (verified rounds 1-8):
//   A[m][k]: m=lane&31, k=(lane>>5)*8+jj
//   B[k][n]: n=lane&31, k=(lane>>5)*8+jj
//   C/D:     col=lane&31, row=(reg&3)+8*(reg>>2)+4*(lane>>5)

#define Z 32
#define ROWS 65536
#define NBLK (ROWS / 64)         // 1024 blocks: 2 tiles x 4 k-splits (4 waves)

#define NCHUNK 552               // quarters: 36 + 84 + 160 + 272
#define NGRAN (NCHUNK * 2)
#define NGP 1120                 // padded mg table (overreads -> 0)
#define KSPAN 138                // chunks per k-split (552/4)

typedef short short8 __attribute__((ext_vector_type(8)));
typedef float f32x16 __attribute__((ext_vector_type(16)));
typedef float float2v __attribute__((ext_vector_type(2)));

struct Sched {
    unsigned mg[NGP];          // (i*128) | (j*128)<<16 byte offs into col-major zs; pad=0
    short rt[NGRAN * 8];       // library row per (granule, jj), -1 = pad
    int nq[4];
};

constexpr Sched make_sched() {
    Sched s{};
    short gi[NGP] = {}, gj[NGP] = {};
    char gt[NGP] = {}, gq[NGP] = {};
    int tidx[32][32] = {}, pidx[32] = {};
    {
        int n = 0;
        for (int a = 0; a < 32; ++a)
            for (int b = a; b < 32; ++b) { tidx[a][b] = n; n += 32 - b; }
        for (int i = 0; i < 32; ++i) pidx[i] = i * 32 - i * (i - 1) / 2;
    }
    int g = 0;
    for (int q = 0; q < 4; ++q) {
        int g0 = g;
        // triples (a<=b): granule covers k in [8q,8q+8) for k>=b -> b>>3 <= q
        for (int b = 0; b < 32; ++b)
            if ((b >> 3) <= q)
                for (int a = 0; a <= b; ++a) { gi[g]=(short)a; gj[g]=(short)b; gt[g]=0; gq[g]=(char)q; ++g; }
        // pairs (b,32): theta = z_b*z_k, valid k<=b -> b>>3 >= q
        for (int b = 0; b < 32; ++b)
            if ((b >> 3) >= q) { gi[g]=(short)b; gj[g]=32; gt[g]=1; gq[g]=(char)q; ++g; }
        // linear: theta = z_k
        gi[g]=32; gj[g]=32; gt[g]=2; gq[g]=(char)q; ++g;
        // pad quarter to a multiple of 8 granules (4 chunks)
        while ((g - g0) & 7) { gi[g]=32; gj[g]=32; gt[g]=3; gq[g]=(char)q; ++g; }
        s.nq[q] = (g - g0) / 2;
    }
    for (int gg = 0; gg < NGRAN; ++gg) {
        s.mg[gg] = ((unsigned)gi[gg] * 128u) | (((unsigned)gj[gg] * 128u) << 16);
        int i = gi[gg], j = gj[gg], ty = gt[gg], q = gq[gg];
        for (int jj = 0; jj < 8; ++jj) {
            int k = 8 * q + jj, row = -1;
            if (ty == 0)      { if (k >= j) row = 561 + tidx[i][j] + (k - j); }   // triple (i,j,k)
            else if (ty == 1) { if (k <= i) row = 33 + pidx[k] + (i - k); }       // pair (k,i)
            else if (ty == 2) { row = 1 + k; }                                    // linear z_k
            s.rt[gg * 8 + jj] = (short)row;
        }
    }
    // [NGRAN,NGP): mg stays 0 -> pipeline overreads hit zs[0][m], never used
    return s;
}
constexpr Sched S = make_sched();
static_assert(S.nq[0] == 36 && S.nq[1] == 84 && S.nq[2] == 160 && S.nq[3] == 272, "chunk counts");

__device__ __forceinline__ unsigned pack_bf16(float s0, float s1) {
#if __has_builtin(__builtin_amdgcn_cvt_pk_bf16_f32)
    return __builtin_bit_cast(unsigned, __builtin_amdgcn_cvt_pk_bf16_f32(s0, s1));
#else
    unsigned b0 = __builtin_bit_cast(unsigned, s0) + 0x8000u;
    unsigned b1 = __builtin_bit_cast(unsigned, s1) + 0x8000u;
    return __builtin_amdgcn_perm(b1, b0, 0x07060302u);   // lo16=s0, hi16=s1
#endif
}

// ---- prep (R7/R8 proven): coalesced, block per 4 granules ----
__global__ void sindy_prep(const float* __restrict__ Xi,
                           const float* __restrict__ Xi_mask,
                           uint2* __restrict__ Bp2, size_t ws_size) {
    __shared__ unsigned short sh[8][32];
    const int tid = threadIdx.x;
    const int jj = tid >> 5, n = tid & 31;
#pragma unroll
    for (int pass = 0; pass < 4; ++pass) {
        int g = blockIdx.x * 4 + pass;
        int row = S.rt[g * 8 + jj];
        float f = 0.0f;
        if (row >= 0) f = Xi[row * Z + n] * Xi_mask[row * Z + n];
        unsigned u = __builtin_bit_cast(unsigned, f);
        sh[jj][n] = (unsigned short)((u + 0x7FFFu + ((u >> 16) & 1u)) >> 16);  // RNE
        __syncthreads();
        if (tid < 64) {
            int n2 = tid & 31, rep = tid >> 5;
            unsigned v0 = sh[4*rep+0][n2], v1 = sh[4*rep+1][n2];
            unsigned v2 = sh[4*rep+2][n2], v3 = sh[4*rep+3][n2];
            int c = g >> 1, h = g & 1;
            size_t idx = ((size_t)c * 64 + h * 32 + n2) * 2 + rep;
            if ((idx + 1) * 8 <= ws_size)
                Bp2[idx] = uint2{v0 | (v1 << 16), v2 | (v3 << 16)};
        }
        __syncthreads();
    }
}

// ---- main: block = 2 tiles x 4 k-splits; wave = BOTH tiles, one k-split ----
__global__ __launch_bounds__(256, 4) void sindy_mfma(const float* __restrict__ z,
                                                     const float* __restrict__ Xi,
                                                     const float* __restrict__ Xi_mask,
                                                     const uint4* __restrict__ Bp,
                                                     float* __restrict__ out) {
    const int lane = threadIdx.x & 63;
    const int kh = threadIdx.x >> 6;     // k-split 0..3
    const int m = lane & 31;
    const int half = lane >> 5;
    const long R = (long)blockIdx.x * 64;   // rows of tile0; tile1 = R+32

    __shared__ float zs[2][33][32];      // col-major zs[t][k][m]; bank = m
    __shared__ float cs[3][2][32][32];   // partials from kh1..3, per tile
    __shared__ unsigned mg_sh[NGP];

    for (int t = threadIdx.x; t < NGP; t += 256) mg_sh[t] = S.mg[t];
    // stage z for 64 rows (coalesced float4 reads)
    for (int idx = threadIdx.x; idx < 512; idx += 256) {
        int row = idx >> 3, q4 = idx & 7;
        float4 v = ((const float4*)(z + (R + row) * Z))[q4];
        int t = row >> 5, mm = row & 31;
        zs[t][4*q4+0][mm] = v.x; zs[t][4*q4+1][mm] = v.y;
        zs[t][4*q4+2][mm] = v.z; zs[t][4*q4+3][mm] = v.w;
    }
    if (threadIdx.x < 64) zs[threadIdx.x >> 5][32][threadIdx.x & 31] = 1.0f;  // z~[32]=1
    __syncthreads();

    const int c0 = kh * KSPAN, cend = c0 + KSPAN;
    const char* zmb0 = (const char*)&zs[0][0][0] + 4 * m;
    const char* zmb1 = (const char*)&zs[1][0][0] + 4 * m;
    const unsigned* mgh = mg_sh + half;

    const uint4* p = Bp + lane + (size_t)c0 * 64;
    uint4 curA = p[0], curB = p[64];

    // prime shallow pipeline (plain scalars, single scope)
    unsigned u0 = mgh[2*c0], u1 = mgh[2*c0+2];
    float pA0 = (*(const float*)(zmb0 + (u0 & 0xFFFFu))) * (*(const float*)(zmb0 + (u0 >> 16)));
    float pA1 = (*(const float*)(zmb1 + (u0 & 0xFFFFu))) * (*(const float*)(zmb1 + (u0 >> 16)));
    float pB0 = (*(const float*)(zmb0 + (u1 & 0xFFFFu))) * (*(const float*)(zmb0 + (u1 >> 16)));
    float pB1 = (*(const float*)(zmb1 + (u1 & 0xFFFFu))) * (*(const float*)(zmb1 + (u1 >> 16)));
    unsigned w0s = mgh[2*c0+4], w1s = mgh[2*c0+6];

    f32x16 acc0 = {}, acc1 = {};

    auto seg = [&](int Q, int cbeg, int cfin, bool lastp) {
        // this quarter's z octets for both tiles (static-per-segment offsets)
        const char* zq0 = zmb0 + Q * 1024;
        const char* zq1 = zmb1 + Q * 1024;
        float2v zA0, zA1, zA2, zA3, zB0, zB1, zB2, zB3;
        zA0.x = *(const float*)(zq0 +   0); zA0.y = *(const float*)(zq0 + 128);
        zA1.x = *(const float*)(zq0 + 256); zA1.y = *(const float*)(zq0 + 384);
        zA2.x = *(const float*)(zq0 + 512); zA2.y = *(const float*)(zq0 + 640);
        zA3.x = *(const float*)(zq0 + 768); zA3.y = *(const float*)(zq0 + 896);
        zB0.x = *(const float*)(zq1 +   0); zB0.y = *(const float*)(zq1 + 128);
        zB1.x = *(const float*)(zq1 + 256); zB1.y = *(const float*)(zq1 + 384);
        zB2.x = *(const float*)(zq1 + 512); zB2.y = *(const float*)(zq1 + 640);
        zB3.x = *(const float*)(zq1 + 768); zB3.y = *(const float*)(zq1 + 896);

        auto mfma0 = [&](float pp, const uint4& bv) {   // tile0
            float2v p2; p2.x = pp; p2.y = pp;
            union { unsigned u[4]; short8 sv; } a;
            float2v t0 = p2 * zA0; a.u[0] = pack_bf16(t0.x, t0.y);
            float2v t1 = p2 * zA1; a.u[1] = pack_bf16(t1.x, t1.y);
            float2v t2 = p2 * zA2; a.u[2] = pack_bf16(t2.x, t2.y);
            float2v t3 = p2 * zA3; a.u[3] = pack_bf16(t3.x, t3.y);
            union { uint4 v; short8 sv; } b; b.v = bv;
            acc0 = __builtin_amdgcn_mfma_f32_32x32x16_bf16(a.sv, b.sv, acc0, 0, 0, 0);
        };
        auto mfma1 = [&](float pp, const uint4& bv) {   // tile1
            float2v p2; p2.x = pp; p2.y = pp;
            union { unsigned u[4]; short8 sv; } a;
            float2v t0 = p2 * zB0; a.u[0] = pack_bf16(t0.x, t0.y);
            float2v t1 = p2 * zB1; a.u[1] = pack_bf16(t1.x, t1.y);
            float2v t2 = p2 * zB2; a.u[2] = pack_bf16(t2.x, t2.y);
            float2v t3 = p2 * zB3; a.u[3] = pack_bf16(t3.x, t3.y);
            union { uint4 v; short8 sv; } b; b.v = bv;
            acc1 = __builtin_amdgcn_mfma_f32_32x32x16_bf16(a.sv, b.sv, acc1, 0, 0, 0);
        };

        for (int c = cbeg; c < cfin; c += 2) {
            // stage 1: mg for iter+2 (chunks c+4, c+5; pad absorbs overread)
            unsigned nw0 = mgh[2*c+8], nw1 = mgh[2*c+10];
            // stage 2: z reads for iter+1 (chunks c+2, c+3) from staged words
            float a0i = *(const float*)(zmb0 + (w0s & 0xFFFFu)), a0j = *(const float*)(zmb0 + (w0s >> 16));
            float a1i = *(const float*)(zmb1 + (w0s & 0xFFFFu)), a1j = *(const float*)(zmb1 + (w0s >> 16));
            float b0i = *(const float*)(zmb0 + (w1s & 0xFFFFu)), b0j = *(const float*)(zmb0 + (w1s >> 16));
            float b1i = *(const float*)(zmb1 + (w1s & 0xFFFFu)), b1j = *(const float*)(zmb1 + (w1s >> 16));
            // stage 3: B prefetch (shared by both tiles)
            int off = (lastp && c + 2 >= cfin) ? 0 : 128;
            uint4 nA = p[off], nB = p[off + 64];
            // 4 MFMAs: 2 chunks x 2 tiles, B shared per chunk
            mfma0(pA0, curA); mfma1(pA1, curA);
            mfma0(pB0, curB); mfma1(pB1, curB);
            // retire
            pA0 = a0i * a0j; pA1 = a1i * a1j; pB0 = b0i * b0j; pB1 = b1i * b1j;
            w0s = nw0; w1s = nw1; curA = nA; curB = nB; p += off;
        }
    };

    // quarter-aligned pieces of this wave's [c0, cend) range
    if (kh == 0)      { seg(0,   0,  36, false); seg(1,  36, 120, false); seg(2, 120, 138, true); }
    else if (kh == 1) { seg(2, 138, 276, true); }
    else if (kh == 2) { seg(2, 276, 280, false); seg(3, 280, 414, true); }
    else              { seg(3, 414, 552, true); }

    // combine: kh1..3 park partials; kh0 reduces + stores both tiles
    if (kh != 0) {
#pragma unroll
        for (int r = 0; r < 16; ++r) {
            int row = (r & 3) + 8 * (r >> 2) + 4 * half;
            cs[kh - 1][0][row][m] = acc0[r];
            cs[kh - 1][1][row][m] = acc1[r];
        }
    }
    __syncthreads();
    if (kh == 0) {
        const float bias = Xi[m] * Xi_mask[m];   // library row 0 (ones), col n = m
        float* o0 = out + R * Z;
        float* o1 = out + (R + 32) * Z;
#pragma unroll
        for (int r = 0; r < 16; ++r) {
            int row = (r & 3) + 8 * (r >> 2) + 4 * half;
            o0[row * Z + m] = acc0[r] + cs[0][0][row][m] + cs[1][0][row][m] + cs[2][0][row][m] + bias;
            o1[row * Z + m] = acc1[r] + cs[0][1][row][m] + cs[1][1][row][m] + cs[2][1][row][m] + bias;
        }
    }
}

extern "C" void kernel_launch(void* const* d_in, const int* in_sizes, int n_in,
                              void* d_out, int out_size, void* d_ws, size_t ws_size,
                              hipStream_t stream) {
    const float* z       = (const float*)d_in[0];
    const float* Xi      = (const float*)d_in[1];
    const float* Xi_mask = (const float*)d_in[2];
    // d_in[3]=z_mean, d_in[4]=z_std: unused by the reference
    float* out = (float*)d_out;
    uint4* Bp  = (uint4*)d_ws;   // NCHUNK*64*16 = 565,248 bytes

    sindy_prep<<<NGRAN / 4, 256, 0, stream>>>(Xi, Xi_mask, (uint2*)d_ws, ws_size);
    sindy_mfma<<<NBLK, 256, 0, stream>>>(z, Xi, Xi_mask, Bp, out);
}